// Round 2
// baseline (247.417 us; speedup 1.0000x reference)
//
#include <hip/hip_runtime.h>

// out[b,i,d] = squash_d( sum_{j,k} X[b,j,d] * W[i,j,k,d] )
// B=128, I=64, J=32, K=16, D=1024. All fp32.
//
// r11: resubmission of r10 (container failed twice = infra flake; no
// correctness verdict, kernel reviewed and in-bounds). r10 analysis:
// top-5 rocprof dispatches are ALL harness fillBuffer (~80us, 512 MiB
// re-poison) -> both our kernels are <78us each; dur_us=245 contains
// >=90us of harness reset inside the timed region. Controllable part:
// caps2_k was latency-bound at 8 waves/CU (512 blk x 4 waves, 2/SIMD,
// VALUBusy ~5%). This round: caps3_k = 1024 thr x 1 d/thread, same 4x4
// (b,i) tile (same 512 MiB L2/L3 traffic, same ig%8 XCD W-locality),
// 16 acc VGPRs -> 8192 waves = 32 waves/CU (4x TLP).
//   Wsum[i,j,d] = sum_k W[i,j,k,d]  (fp32, 8 MiB in d_ws)  [unchanged]

constexpr int B_SZ = 128, I_CH = 64, J_CH = 32, K_CAP = 16, D_DIM = 1024;

// Kernel A: Wsum[i,j,d] = sum_k W[i,j,k,d].  Unchanged (BW-bound ~22us:
// reads 128 MiB once, coalesced float4, 2048 blocks = full occupancy).
__global__ __launch_bounds__(256) void wsum_k(const float* __restrict__ W,
                                              float* __restrict__ Wsum) {
    int idx = blockIdx.x * 256 + threadIdx.x;   // over IJ * (D/4) = 2048*256
    int d4 = idx & 255;
    int ij = idx >> 8;
    const float4* Wv = (const float4*)(W + (size_t)ij * K_CAP * D_DIM) + d4;
    float4 acc = make_float4(0.f, 0.f, 0.f, 0.f);
#pragma unroll
    for (int k = 0; k < K_CAP; ++k) {
        float4 w = Wv[k * (D_DIM / 4)];
        acc.x += w.x; acc.y += w.y; acc.z += w.z; acc.w += w.w;
    }
    ((float4*)(Wsum + (size_t)ij * D_DIM))[d4] = acc;
}

// Kernel B v3: 4x4 (b,i) tile per block, 1024 threads, 1 d per thread.
// 512 blocks x 16 waves = 8192 waves = 32/CU (was 8/CU). Per block: 4 X-rows
// + 4 Wsum-rows (1 MiB) for 16 output rows; total reads 512 MiB (L2/L3-hot:
// ig = bid&15 keeps each Wsum i-slice pinned to one XCD's L2; X streams L3).
__global__ __launch_bounds__(1024) void caps3_k(const float* __restrict__ X,
                                                const float* __restrict__ Wsum,
                                                float* __restrict__ out) {
    int t  = threadIdx.x;              // 0..1023 = d index
    int ig = blockIdx.x & 15;          // i-group: i = ig*4 .. ig*4+3
    int bg = blockIdx.x >> 4;          // b-group: b = bg*4 .. bg*4+3
    const float* Xb = X    + (size_t)(bg * 4) * J_CH * D_DIM + t;
    const float* Wb = Wsum + (size_t)(ig * 4) * J_CH * D_DIM + t;

    float s[4][4];                     // [bb][ii], 16 acc VGPRs
#pragma unroll
    for (int bb = 0; bb < 4; ++bb)
#pragma unroll
        for (int ii = 0; ii < 4; ++ii) s[bb][ii] = 0.f;

#pragma unroll 2
    for (int j = 0; j < J_CH; ++j) {
        float xv[4], wv[4];
#pragma unroll
        for (int bb = 0; bb < 4; ++bb)
            xv[bb] = Xb[(size_t)bb * J_CH * D_DIM + j * D_DIM];
#pragma unroll
        for (int ii = 0; ii < 4; ++ii)
            wv[ii] = Wb[(size_t)ii * J_CH * D_DIM + j * D_DIM];
#pragma unroll
        for (int bb = 0; bb < 4; ++bb)
#pragma unroll
            for (int ii = 0; ii < 4; ++ii)
                s[bb][ii] += xv[bb] * wv[ii];
    }

    // Per-(bb,ii) sum of squares over all 1024 d: wave shuffle + LDS combine.
    __shared__ float red[16][16];      // [wave][pair]
    __shared__ float scl[16];
    int lane = t & 63, wid = t >> 6;
#pragma unroll
    for (int p = 0; p < 16; ++p) {
        float ss = s[p >> 2][p & 3];
        ss *= ss;
#pragma unroll
        for (int off = 32; off > 0; off >>= 1) ss += __shfl_down(ss, off, 64);
        if (lane == 0) red[wid][p] = ss;
    }
    __syncthreads();
    if (t < 16) {
        float n2 = 0.f;
#pragma unroll
        for (int w = 0; w < 16; ++w) n2 += red[w][t];
        float n  = sqrtf(n2);
        scl[t] = n2 / (1.0f + n2) / (n + 1e-8f);
    }
    __syncthreads();

#pragma unroll
    for (int bb = 0; bb < 4; ++bb)
#pragma unroll
        for (int ii = 0; ii < 4; ++ii)
            out[((size_t)(bg * 4 + bb) * I_CH + ig * 4 + ii) * D_DIM + t] =
                s[bb][ii] * scl[bb * 4 + ii];
}

extern "C" void kernel_launch(void* const* d_in, const int* in_sizes, int n_in,
                              void* d_out, int out_size, void* d_ws, size_t ws_size,
                              hipStream_t stream) {
    const float* X = (const float*)d_in[0];   // [B,J,D] fp32
    const float* W = (const float*)d_in[1];   // [I,J,K,D] fp32
    float* out = (float*)d_out;               // [B,I,D] fp32
    float* Wsum = (float*)d_ws;               // [I,J,D] fp32, 8 MiB

    wsum_k<<<2048, 256, 0, stream>>>(W, Wsum);
    caps3_k<<<(B_SZ / 4) * (I_CH / 4), 1024, 0, stream>>>(X, Wsum, out);
}

// Round 3
// 244.451 us; speedup vs baseline: 1.0121x; 1.0121x over previous
//
#include <hip/hip_runtime.h>

// out[b,i,d] = squash_d( sum_{j,k} X[b,j,d] * W[i,j,k,d] )
// B=128, I=64, J=32, K=16, D=1024. All fp32.
//
// r12: r11 (4x TLP) was a no-op (245->247) -> confirms timed region is
// ~158us harness fills (2 x 79us 512MiB poisons per iter, from timestamp
// deltas) + ~50us our kernels + gaps. Remaining lever: caps' 512 MiB cache
// traffic = X 256 MiB (L3, expensive) + Wsum 256 MiB (L2-pinned, cheap).
// Flip tile 4bx4i -> 4bx8i: X replication 16->8 (L3 128 MiB), Wsum
// replication 16->32 (L2 256 MiB, cheap). ig = bid&7 -> each XCD owns ONE
// ig group -> Wsum working set 1 MiB/XCD, L2-resident.
//   Wsum[i,j,d] = sum_k W[i,j,k,d]  (fp32, 8 MiB in d_ws)  [unchanged]

constexpr int B_SZ = 128, I_CH = 64, J_CH = 32, K_CAP = 16, D_DIM = 1024;

// Kernel A: Wsum[i,j,d] = sum_k W[i,j,k,d].  BW-bound: 128 MiB HBM read
// (~21us floor), coalesced float4, 2048 blocks.
__global__ __launch_bounds__(256) void wsum_k(const float* __restrict__ W,
                                              float* __restrict__ Wsum) {
    int idx = blockIdx.x * 256 + threadIdx.x;   // over IJ * (D/4) = 2048*256
    int d4 = idx & 255;
    int ij = idx >> 8;
    const float4* Wv = (const float4*)(W + (size_t)ij * K_CAP * D_DIM) + d4;
    float4 acc = make_float4(0.f, 0.f, 0.f, 0.f);
#pragma unroll
    for (int k = 0; k < K_CAP; ++k) {
        float4 w = Wv[k * (D_DIM / 4)];
        acc.x += w.x; acc.y += w.y; acc.z += w.z; acc.w += w.w;
    }
    ((float4*)(Wsum + (size_t)ij * D_DIM))[d4] = acc;
}

// Kernel B v4: 4b x 8i tile per block, 1024 threads, 1 d per thread.
// Grid 256 = 32 bGroups x 8 iGroups -> 1 block/CU, 16 waves/CU.
// Per block: 4 X-rows + 8 Wsum-rows = 1.5 MiB for 32 output rows.
// Chip traffic: X 8x16=128 MiB (L3), Wsum 32x8=256 MiB (L2: ig=bid&7
// pins one 1 MiB Wsum slice per XCD), out 32 MiB write.
__global__ __launch_bounds__(1024) void caps4_k(const float* __restrict__ X,
                                                const float* __restrict__ Wsum,
                                                float* __restrict__ out) {
    int t  = threadIdx.x;              // 0..1023 = d index
    int ig = blockIdx.x & 7;           // i-group: i = ig*8 .. ig*8+7
    int bg = blockIdx.x >> 3;          // b-group: b = bg*4 .. bg*4+3
    const float* Xb = X    + (size_t)(bg * 4) * J_CH * D_DIM + t;
    const float* Wb = Wsum + (size_t)(ig * 8) * J_CH * D_DIM + t;

    float s[4][8];                     // [bb][ii], 32 acc VGPRs
#pragma unroll
    for (int bb = 0; bb < 4; ++bb)
#pragma unroll
        for (int ii = 0; ii < 8; ++ii) s[bb][ii] = 0.f;

#pragma unroll 2
    for (int j = 0; j < J_CH; ++j) {
        float xv[4], wv[8];
#pragma unroll
        for (int bb = 0; bb < 4; ++bb)
            xv[bb] = Xb[(size_t)bb * J_CH * D_DIM + j * D_DIM];
#pragma unroll
        for (int ii = 0; ii < 8; ++ii)
            wv[ii] = Wb[(size_t)ii * J_CH * D_DIM + j * D_DIM];
#pragma unroll
        for (int bb = 0; bb < 4; ++bb)
#pragma unroll
            for (int ii = 0; ii < 8; ++ii)
                s[bb][ii] += xv[bb] * wv[ii];
    }

    // Per-(bb,ii) sum of squares over all 1024 d: wave shuffle + LDS combine.
    __shared__ float red[16][32];      // [wave][pair]  2 KB
    __shared__ float scl[32];
    int lane = t & 63, wid = t >> 6;
#pragma unroll
    for (int p = 0; p < 32; ++p) {
        float ss = s[p >> 3][p & 7];
        ss *= ss;
#pragma unroll
        for (int off = 32; off > 0; off >>= 1) ss += __shfl_down(ss, off, 64);
        if (lane == 0) red[wid][p] = ss;
    }
    __syncthreads();
    if (t < 32) {
        float n2 = 0.f;
#pragma unroll
        for (int w = 0; w < 16; ++w) n2 += red[w][t];
        float n  = sqrtf(n2);
        scl[t] = n2 / (1.0f + n2) / (n + 1e-8f);
    }
    __syncthreads();

#pragma unroll
    for (int bb = 0; bb < 4; ++bb)
#pragma unroll
        for (int ii = 0; ii < 8; ++ii)
            out[((size_t)(bg * 4 + bb) * I_CH + ig * 8 + ii) * D_DIM + t] =
                s[bb][ii] * scl[bb * 8 + ii];
}

extern "C" void kernel_launch(void* const* d_in, const int* in_sizes, int n_in,
                              void* d_out, int out_size, void* d_ws, size_t ws_size,
                              hipStream_t stream) {
    const float* X = (const float*)d_in[0];   // [B,J,D] fp32
    const float* W = (const float*)d_in[1];   // [I,J,K,D] fp32
    float* out = (float*)d_out;               // [B,I,D] fp32
    float* Wsum = (float*)d_ws;               // [I,J,D] fp32, 8 MiB

    wsum_k<<<2048, 256, 0, stream>>>(W, Wsum);
    caps4_k<<<(B_SZ / 4) * (I_CH / 8), 1024, 0, stream>>>(X, Wsum, out);
}